// Round 1
// 363.307 us; speedup vs baseline: 1.0301x; 1.0301x over previous
//
#include <hip/hip_runtime.h>
#include <hip/hip_bf16.h>
#include <stdint.h>

#define B_ROWS 16384
#define IN_DIM 2048
#define OUT_DIM 2048

typedef __attribute__((ext_vector_type(4))) float f32x4;
typedef __attribute__((ext_vector_type(8))) short s16x8;

__device__ __forceinline__ unsigned short f2bf_rne(float f) {
  union { float f; unsigned u; } c; c.f = f;
  unsigned u = c.u;
  return (unsigned short)((u + 0x7FFFu + ((u >> 16) & 1u)) >> 16);
}

// Fused prep: blocks [0, 4096) handle x (one WAVE per row: bf16 cast + L2 norm);
// blocks [4096, 6144) handle W (fp32 -> bf16, 8 elems/thread).  UNCHANGED this round.
#define PREP_X_BLOCKS 4096
#define PREP_W_BLOCKS 2048

__global__ void __launch_bounds__(256) prep_kernel(const float* __restrict__ x,
                                                   unsigned short* __restrict__ xn,
                                                   float* __restrict__ scale,
                                                   const float* __restrict__ W,
                                                   unsigned short* __restrict__ Wb) {
  if (blockIdx.x < PREP_X_BLOCKS) {
    const int row  = (blockIdx.x * 256 + threadIdx.x) >> 6;
    const int lane = threadIdx.x & 63;
    const float4* xr = (const float4*)(x + (size_t)row * IN_DIM);
    unsigned short* xrow = xn + (size_t)row * IN_DIM;

    float ss = 0.0f;
    #pragma unroll
    for (int j = 0; j < 4; ++j) {
      const int f4 = j * 128 + lane * 2;   // float4 index within the row
      float4 v0 = xr[f4 + 0];
      float4 v1 = xr[f4 + 1];
      ss += v0.x * v0.x + v0.y * v0.y + v0.z * v0.z + v0.w * v0.w +
            v1.x * v1.x + v1.y * v1.y + v1.z * v1.z + v1.w * v1.w;
      s16x8 p;
      p[0] = (short)f2bf_rne(v0.x); p[1] = (short)f2bf_rne(v0.y);
      p[2] = (short)f2bf_rne(v0.z); p[3] = (short)f2bf_rne(v0.w);
      p[4] = (short)f2bf_rne(v1.x); p[5] = (short)f2bf_rne(v1.y);
      p[6] = (short)f2bf_rne(v1.z); p[7] = (short)f2bf_rne(v1.w);
      *(s16x8*)(xrow + f4 * 4) = p;
    }

    #pragma unroll
    for (int m = 32; m > 0; m >>= 1) ss += __shfl_xor(ss, m, 64);
    if (lane == 0) scale[row] = 1.0f / (sqrtf(ss) + 1e-4f);
  } else {
    const size_t base = (size_t)(blockIdx.x - PREP_X_BLOCKS) * 2048 +
                        (size_t)threadIdx.x * 8;
    const float4* wp = (const float4*)(W + base);
    float4 v0 = wp[0];
    float4 v1 = wp[1];
    s16x8 p;
    p[0] = (short)f2bf_rne(v0.x); p[1] = (short)f2bf_rne(v0.y);
    p[2] = (short)f2bf_rne(v0.z); p[3] = (short)f2bf_rne(v0.w);
    p[4] = (short)f2bf_rne(v1.x); p[5] = (short)f2bf_rne(v1.y);
    p[6] = (short)f2bf_rne(v1.z); p[7] = (short)f2bf_rne(v1.w);
    *(s16x8*)(Wb + base) = p;
  }
}

// ===========================================================================
// 256x256 tile, BK=64, 512 threads (8 waves, 2Mx4N), per-wave 128x64 output.
// 4-phase pipelined K-loop (T3+T4+T5 from the technique catalog):
//   phase = { setprio1; 16 MFMA (regs read last phase); setprio0;
//             ds_reads for NEXT phase's MFMA; 2x global_load_lds stage;
//             [counted vmcnt]; s_barrier }
// Stage order per tile T (for tile T+1): ph1=B rows 0-127, ph2=B rows 128-255,
// ph3=A rows {0-63,128-191} (even quarters, needed by mi0-3 reads),
// ph4=A rows {64-127,192-255} (odd quarters, needed by mi4-7 reads).
// Waits: vmcnt(4) end-ph2 (A-odd of T landed), vmcnt(2) end-ph4 (B + A-even
// of T+1 landed).  Never vmcnt(0) in the main loop; raw s_barrier only so the
// compiler cannot insert a drain.  MFMA groups lag reads by one phase:
//   ph1: mi4-7 x kk1 of T-1   (first iter: zero-init frags -> no-op)
//   ph2: mi0-3 x kk0 of T, ph3: mi0-3 x kk1, ph4: mi4-7 x kk0.
// LDS: 2 buffers x (A 32KB + B 32KB) = 128 KiB; same XOR-8 chunk swizzle as
// before (measured 0 bank conflicts): phys 16B-chunk p at row r holds logical
// chunk p^(r&7); staging pre-swizzles the GLOBAL column, LDS dest stays
// linear (tid*16) as global_load_lds requires.
// ===========================================================================

#define GLD16(SRC, DST)                                                        \
  __builtin_amdgcn_global_load_lds(                                            \
      (const __attribute__((address_space(1))) unsigned int*)(SRC),            \
      (__attribute__((address_space(3))) unsigned int*)(DST), 16, 0, 0)

__global__ void __launch_bounds__(512, 1) gemm_kernel(const unsigned short* __restrict__ A,
                                                      const unsigned short* __restrict__ Bm,
                                                      const float* __restrict__ scale,
                                                      const float* __restrict__ bias,
                                                      float* __restrict__ out) {
  __shared__ unsigned short As[2][256 * 64];
  __shared__ unsigned short Bs[2][256 * 64];

  const int tid = threadIdx.x;
  const int bid = blockIdx.x;
  // XCD swizzle: round-robin dispatch -> bid&7 is the XCD. Each XCD owns 8
  // consecutive bm (1MB A-slab stays in its L2) and sweeps all 8 bn.
  const int xcd = bid & 7;
  const int loc = bid >> 3;               // 0..63
  const int bm  = xcd * 8 + (loc >> 3);   // 0..63
  const int bn  = loc & 7;                // 0..7

  const int lane = tid & 63;
  const int wave = tid >> 6;              // 0..7
  const int wm   = wave >> 2;             // 0..1
  const int wn   = wave & 3;              // 0..3
  const int lrow = lane & 15;
  const int lq   = lane >> 4;

  // --- staging addresses: thread t = row (t>>3), chunk (t&7) of a 64-row
  // block; LDS dest linear at byte t*16; global col pre-swizzled.
  const int sr = tid >> 3;
  const int sc = tid & 7;
  const unsigned short* aG = A  + (size_t)(bm * 256 + sr) * IN_DIM + ((sc ^ (sr & 7)) * 8);
  const unsigned short* bG = Bm + (size_t)(bn * 256 + sr) * IN_DIM + ((sc ^ (sr & 7)) * 8);

  // --- fragment read bases (element offsets into a 256x64 buffer)
  const int aRow = (wm * 128 + lrow) * 64;
  const int bRow = (wn * 64  + lrow) * 64;
  const int c0   = (lq ^ (lrow & 7)) * 8;   // kk=0 chunk; kk=1 chunk = c0^32

  f32x4 acc[8][4] = {};
  s16x8 af[4] = {};       // zero-init: makes the first ph1 MFMA group a no-op
  s16x8 bf[4][2] = {};

  // --- prologue: stage tile 0 into buf0, order Bh0,Bh1,A-even,A-odd
  {
    char* aD = (char*)&As[0][0] + tid * 16;
    char* bD = (char*)&Bs[0][0] + tid * 16;
    GLD16(bG,                         bD);
    GLD16(bG + (size_t) 64 * IN_DIM,  bD + 8192);
    GLD16(bG + (size_t)128 * IN_DIM,  bD + 16384);
    GLD16(bG + (size_t)192 * IN_DIM,  bD + 24576);
    GLD16(aG,                         aD);
    GLD16(aG + (size_t)128 * IN_DIM,  aD + 16384);
    GLD16(aG + (size_t) 64 * IN_DIM,  aD + 8192);
    GLD16(aG + (size_t)192 * IN_DIM,  aD + 24576);
  }
  asm volatile("s_waitcnt vmcnt(2)" ::: "memory");  // B(0)+A-even(0) landed
  __builtin_amdgcn_s_barrier();

  for (int T = 0; T < IN_DIM / 64; ++T) {
    const int cur = T & 1, nxt = cur ^ 1;
    const size_t kN = (size_t)((T < IN_DIM / 64 - 1) ? (T + 1) * 64 : 0);  // clamp: last prefetch is dead
    char* aD = (char*)&As[nxt][0] + tid * 16;
    char* bD = (char*)&Bs[nxt][0] + tid * 16;
    const unsigned short* aS = aG + kN;
    const unsigned short* bS = bG + kN;

    // ---------- ph1: MFMA G4(T-1) | read bf(T) all + af mi0-3 kk0 | stage B-h0(T+1)
    __builtin_amdgcn_s_setprio(1);
    #pragma unroll
    for (int mi = 0; mi < 4; ++mi)
      #pragma unroll
      for (int ni = 0; ni < 4; ++ni)
        acc[4 + mi][ni] = __builtin_amdgcn_mfma_f32_16x16x32_bf16(af[mi], bf[ni][1], acc[4 + mi][ni], 0, 0, 0);
    __builtin_amdgcn_s_setprio(0);
    #pragma unroll
    for (int ni = 0; ni < 4; ++ni) {
      bf[ni][0] = *(const s16x8*)(&Bs[cur][bRow + ni * 1024 + c0]);
      bf[ni][1] = *(const s16x8*)(&Bs[cur][bRow + ni * 1024 + (c0 ^ 32)]);
    }
    #pragma unroll
    for (int mi = 0; mi < 4; ++mi)
      af[mi] = *(const s16x8*)(&As[cur][aRow + mi * 1024 + c0]);
    GLD16(bS,                        bD);
    GLD16(bS + (size_t)64 * IN_DIM,  bD + 8192);
    __builtin_amdgcn_s_barrier();

    // ---------- ph2: MFMA G1 (mi0-3,kk0) | read af mi0-3 kk1 | stage B-h1(T+1) | vmcnt(4)
    __builtin_amdgcn_s_setprio(1);
    #pragma unroll
    for (int mi = 0; mi < 4; ++mi)
      #pragma unroll
      for (int ni = 0; ni < 4; ++ni)
        acc[mi][ni] = __builtin_amdgcn_mfma_f32_16x16x32_bf16(af[mi], bf[ni][0], acc[mi][ni], 0, 0, 0);
    __builtin_amdgcn_s_setprio(0);
    #pragma unroll
    for (int mi = 0; mi < 4; ++mi)
      af[mi] = *(const s16x8*)(&As[cur][aRow + mi * 1024 + (c0 ^ 32)]);
    GLD16(bS + (size_t)128 * IN_DIM, bD + 16384);
    GLD16(bS + (size_t)192 * IN_DIM, bD + 24576);
    asm volatile("s_waitcnt vmcnt(4)" ::: "memory");  // A-odd(T) landed (for ph3 reads)
    __builtin_amdgcn_s_barrier();

    // ---------- ph3: MFMA G2 (mi0-3,kk1) | read af mi4-7 kk0 | stage A-even(T+1)
    __builtin_amdgcn_s_setprio(1);
    #pragma unroll
    for (int mi = 0; mi < 4; ++mi)
      #pragma unroll
      for (int ni = 0; ni < 4; ++ni)
        acc[mi][ni] = __builtin_amdgcn_mfma_f32_16x16x32_bf16(af[mi], bf[ni][1], acc[mi][ni], 0, 0, 0);
    __builtin_amdgcn_s_setprio(0);
    #pragma unroll
    for (int mi = 0; mi < 4; ++mi)
      af[mi] = *(const s16x8*)(&As[cur][aRow + (4 + mi) * 1024 + c0]);
    GLD16(aS,                        aD);
    GLD16(aS + (size_t)128 * IN_DIM, aD + 16384);
    __builtin_amdgcn_s_barrier();

    // ---------- ph4: MFMA G3 (mi4-7,kk0) | read af mi4-7 kk1 | stage A-odd(T+1) | vmcnt(2)
    __builtin_amdgcn_s_setprio(1);
    #pragma unroll
    for (int mi = 0; mi < 4; ++mi)
      #pragma unroll
      for (int ni = 0; ni < 4; ++ni)
        acc[4 + mi][ni] = __builtin_amdgcn_mfma_f32_16x16x32_bf16(af[mi], bf[ni][0], acc[4 + mi][ni], 0, 0, 0);
    __builtin_amdgcn_s_setprio(0);
    #pragma unroll
    for (int mi = 0; mi < 4; ++mi)
      af[mi] = *(const s16x8*)(&As[cur][aRow + (4 + mi) * 1024 + (c0 ^ 32)]);
    GLD16(aS + (size_t)64  * IN_DIM, aD + 8192);
    GLD16(aS + (size_t)192 * IN_DIM, aD + 24576);
    asm volatile("s_waitcnt vmcnt(2)" ::: "memory");  // B(T+1)+A-even(T+1) landed (for ph1 reads)
    __builtin_amdgcn_s_barrier();
  }

  // ---------- tail: G4 of the last tile
  __builtin_amdgcn_s_setprio(1);
  #pragma unroll
  for (int mi = 0; mi < 4; ++mi)
    #pragma unroll
    for (int ni = 0; ni < 4; ++ni)
      acc[4 + mi][ni] = __builtin_amdgcn_mfma_f32_16x16x32_bf16(af[mi], bf[ni][1], acc[4 + mi][ni], 0, 0, 0);
  __builtin_amdgcn_s_setprio(0);

  // ---------- epilogue: D lane map col=lane&15, row=(lane>>4)*4 + r
  const int row0 = bm * 256 + wm * 128 + lq * 4;
  const int col0 = bn * 256 + wn * 64 + lrow;
  #pragma unroll
  for (int mi = 0; mi < 8; ++mi) {
    const int row = row0 + mi * 16;
    const f32x4 sc4 = *(const f32x4*)(scale + row);
    #pragma unroll
    for (int ni = 0; ni < 4; ++ni) {
      const int col = col0 + ni * 16;
      const float bcol = bias[col];
      #pragma unroll
      for (int r = 0; r < 4; ++r) {
        float v = acc[mi][ni][r] * sc4[r] + bcol;
        out[(size_t)(row + r) * OUT_DIM + col] = fmaxf(v, 0.0f);
      }
    }
  }
}

extern "C" void kernel_launch(void* const* d_in, const int* in_sizes, int n_in,
                              void* d_out, int out_size, void* d_ws, size_t ws_size,
                              hipStream_t stream) {
  const float* x = (const float*)d_in[0];
  const float* W = (const float*)d_in[1];
  const float* b = (const float*)d_in[2];
  float* out = (float*)d_out;

  char* ws = (char*)d_ws;
  unsigned short* xn    = (unsigned short*)ws;                                  // 67108864 B
  unsigned short* Wb    = (unsigned short*)(ws + (size_t)67108864);             //  8388608 B
  float*          scale = (float*)(ws + (size_t)67108864 + (size_t)8388608);    //    65536 B

  prep_kernel<<<PREP_X_BLOCKS + PREP_W_BLOCKS, 256, 0, stream>>>(x, xn, scale, W, Wb);

  gemm_kernel<<<(OUT_DIM / 256) * (B_ROWS / 256), 512, 0, stream>>>(xn, Wb, scale, b, out);
}

// Round 2
// 356.401 us; speedup vs baseline: 1.0500x; 1.0194x over previous
//
#include <hip/hip_runtime.h>
#include <hip/hip_bf16.h>
#include <stdint.h>

#define B_ROWS 16384
#define IN_DIM 2048
#define OUT_DIM 2048

typedef __attribute__((ext_vector_type(4))) float f32x4;
typedef __attribute__((ext_vector_type(8))) short s16x8;

__device__ __forceinline__ unsigned short f2bf_rne(float f) {
  union { float f; unsigned u; } c; c.f = f;
  unsigned u = c.u;
  return (unsigned short)((u + 0x7FFFu + ((u >> 16) & 1u)) >> 16);
}

// Fused prep: blocks [0, 4096) handle x (one WAVE per row: bf16 cast + L2 norm);
// blocks [4096, 6144) handle W (fp32 -> bf16, 8 elems/thread).  UNCHANGED this round.
#define PREP_X_BLOCKS 4096
#define PREP_W_BLOCKS 2048

__global__ void __launch_bounds__(256) prep_kernel(const float* __restrict__ x,
                                                   unsigned short* __restrict__ xn,
                                                   float* __restrict__ scale,
                                                   const float* __restrict__ W,
                                                   unsigned short* __restrict__ Wb) {
  if (blockIdx.x < PREP_X_BLOCKS) {
    const int row  = (blockIdx.x * 256 + threadIdx.x) >> 6;
    const int lane = threadIdx.x & 63;
    const float4* xr = (const float4*)(x + (size_t)row * IN_DIM);
    unsigned short* xrow = xn + (size_t)row * IN_DIM;

    float ss = 0.0f;
    #pragma unroll
    for (int j = 0; j < 4; ++j) {
      const int f4 = j * 128 + lane * 2;   // float4 index within the row
      float4 v0 = xr[f4 + 0];
      float4 v1 = xr[f4 + 1];
      ss += v0.x * v0.x + v0.y * v0.y + v0.z * v0.z + v0.w * v0.w +
            v1.x * v1.x + v1.y * v1.y + v1.z * v1.z + v1.w * v1.w;
      s16x8 p;
      p[0] = (short)f2bf_rne(v0.x); p[1] = (short)f2bf_rne(v0.y);
      p[2] = (short)f2bf_rne(v0.z); p[3] = (short)f2bf_rne(v0.w);
      p[4] = (short)f2bf_rne(v1.x); p[5] = (short)f2bf_rne(v1.y);
      p[6] = (short)f2bf_rne(v1.z); p[7] = (short)f2bf_rne(v1.w);
      *(s16x8*)(xrow + f4 * 4) = p;
    }

    #pragma unroll
    for (int m = 32; m > 0; m >>= 1) ss += __shfl_xor(ss, m, 64);
    if (lane == 0) scale[row] = 1.0f / (sqrtf(ss) + 1e-4f);
  } else {
    const size_t base = (size_t)(blockIdx.x - PREP_X_BLOCKS) * 2048 +
                        (size_t)threadIdx.x * 8;
    const float4* wp = (const float4*)(W + base);
    float4 v0 = wp[0];
    float4 v1 = wp[1];
    s16x8 p;
    p[0] = (short)f2bf_rne(v0.x); p[1] = (short)f2bf_rne(v0.y);
    p[2] = (short)f2bf_rne(v0.z); p[3] = (short)f2bf_rne(v0.w);
    p[4] = (short)f2bf_rne(v1.x); p[5] = (short)f2bf_rne(v1.y);
    p[6] = (short)f2bf_rne(v1.z); p[7] = (short)f2bf_rne(v1.w);
    *(s16x8*)(Wb + base) = p;
  }
}

// ===========================================================================
// 256x256 tile, BK=64, 512 threads (8 waves 2Mx4N), per-wave 128x64, acc[8][4].
// SAME-PHASE schedule (m201 shape): each phase = { ds_read this phase's frags;
// stage 2x global_load_lds; s_barrier; setprio1; 16 MFMA; setprio0; [vmcnt];
// s_barrier }.  The lgkmcnt before MFMA (compiler-inserted) is satisfied in
// LDS-queue order -> waves enter the MFMA cluster STAGGERED -> matrix pipe and
// LDS pipe overlap across waves.  (R1's one-phase-lag variant de-staggered the
// waves into pipe-type lockstep: MFMA 46% + LDS 43% + VALU 18% fully serial.)
// Phase->MFMA-group map (per wave, m-sub = its 64-row half, kk = K:32 half):
//   ph1 G1=(msub0,kk0): reads a0-3 kk0 + bf[*][0]  (8 reads), stage B-h0(T+1)
//   ph2 G2=(msub0,kk1): reads a0-3 kk1 + bf[*][1]  (8 reads), stage B-h1(T+1), vmcnt(4)
//   ph3 G3=(msub1,kk0): reads a4-7 kk0             (4 reads), stage A-even(T+1)
//   ph4 G4=(msub1,kk1): reads a4-7 kk1             (4 reads), stage A-odd(T+1), vmcnt(2)
// bf[4][2] stays live across the tile.  Ledger (verified, steady state):
//   enter ph1: 2 outstanding (A-odd(T));  ph1 +2 -> 4;  ph2 +2 -> 6,
//   vmcnt(4) waits A-odd(T) [needed ph3 reads];  ph3 +2 -> 6;  ph4 +2 -> 8,
//   vmcnt(2) waits B+A-even(T+1) [needed T+1 ph1/ph2 reads], leaves A-odd(T+1).
// All staging writes target buf[nxt] only and are issued after the barrier
// closing all reads of that buffer -> no LDS write/read race.  Never vmcnt(0).
// LDS XOR-8 chunk swizzle unchanged (0 bank conflicts measured).
// ===========================================================================

#define GLD16(SRC, DST)                                                        \
  __builtin_amdgcn_global_load_lds(                                            \
      (const __attribute__((address_space(1))) unsigned int*)(SRC),            \
      (__attribute__((address_space(3))) unsigned int*)(DST), 16, 0, 0)

__global__ void __launch_bounds__(512, 1) gemm_kernel(const unsigned short* __restrict__ A,
                                                      const unsigned short* __restrict__ Bm,
                                                      const float* __restrict__ scale,
                                                      const float* __restrict__ bias,
                                                      float* __restrict__ out) {
  __shared__ unsigned short As[2][256 * 64];
  __shared__ unsigned short Bs[2][256 * 64];

  const int tid = threadIdx.x;
  const int bid = blockIdx.x;
  // XCD swizzle: round-robin dispatch -> bid&7 is the XCD. Each XCD owns 8
  // consecutive bm (1MB A-slab stays in its L2) and sweeps all 8 bn.
  const int xcd = bid & 7;
  const int loc = bid >> 3;               // 0..63
  const int bm  = xcd * 8 + (loc >> 3);   // 0..63
  const int bn  = loc & 7;                // 0..7

  const int lane = tid & 63;
  const int wave = tid >> 6;              // 0..7
  const int wm   = wave >> 2;             // 0..1
  const int wn   = wave & 3;              // 0..3
  const int lrow = lane & 15;
  const int lq   = lane >> 4;

  // --- staging: thread t = row (t>>3), chunk (t&7) of a 64-row block;
  // LDS dest linear at byte t*16; global col pre-swizzled (XOR-8).
  const int sr = tid >> 3;
  const int sc = tid & 7;
  const unsigned short* aG = A  + (size_t)(bm * 256 + sr) * IN_DIM + ((sc ^ (sr & 7)) * 8);
  const unsigned short* bG = Bm + (size_t)(bn * 256 + sr) * IN_DIM + ((sc ^ (sr & 7)) * 8);

  // --- fragment read bases (element offsets into a 256x64 buffer)
  const int aRow = (wm * 128 + lrow) * 64;
  const int bRow = (wn * 64  + lrow) * 64;
  const int c0   = (lq ^ (lrow & 7)) * 8;   // kk=0 chunk; kk=1 chunk = c0^32

  f32x4 acc[8][4] = {};
  s16x8 bf[4][2];

  // --- prologue: stage tile 0 into buf0: B-h0, B-h1, A-even, A-odd
  {
    char* aD = (char*)&As[0][0] + tid * 16;
    char* bD = (char*)&Bs[0][0] + tid * 16;
    GLD16(bG,                         bD);
    GLD16(bG + (size_t) 64 * IN_DIM,  bD + 8192);
    GLD16(bG + (size_t)128 * IN_DIM,  bD + 16384);
    GLD16(bG + (size_t)192 * IN_DIM,  bD + 24576);
    GLD16(aG,                         aD);          // rows   0- 63 (msub0, wm0)
    GLD16(aG + (size_t)128 * IN_DIM,  aD + 16384);  // rows 128-191 (msub0, wm1)
    GLD16(aG + (size_t) 64 * IN_DIM,  aD + 8192);   // rows  64-127 (msub1, wm0)
    GLD16(aG + (size_t)192 * IN_DIM,  aD + 24576);  // rows 192-255 (msub1, wm1)
  }
  asm volatile("s_waitcnt vmcnt(2)" ::: "memory");  // B(0)+A-even(0) landed
  __builtin_amdgcn_s_barrier();

  for (int T = 0; T < IN_DIM / 64; ++T) {
    const int cur = T & 1, nxt = cur ^ 1;
    const size_t kN = (size_t)((T < IN_DIM / 64 - 1) ? (T + 1) * 64 : 0);  // last prefetch is dead
    char* aD = (char*)&As[nxt][0] + tid * 16;
    char* bD = (char*)&Bs[nxt][0] + tid * 16;
    const unsigned short* aS = aG + kN;
    const unsigned short* bS = bG + kN;
    const unsigned short* Ac = &As[cur][0];
    const unsigned short* Bc = &Bs[cur][0];

    // ---------- ph1: G1=(msub0,kk0) | stage B-h0(T+1)
    {
      s16x8 a[4];
      #pragma unroll
      for (int mi = 0; mi < 4; ++mi)
        a[mi] = *(const s16x8*)(Ac + aRow + mi * 1024 + c0);
      #pragma unroll
      for (int ni = 0; ni < 4; ++ni)
        bf[ni][0] = *(const s16x8*)(Bc + bRow + ni * 1024 + c0);
      GLD16(bS,                        bD);
      GLD16(bS + (size_t)64 * IN_DIM,  bD + 8192);
      __builtin_amdgcn_s_barrier();
      __builtin_amdgcn_s_setprio(1);
      #pragma unroll
      for (int mi = 0; mi < 4; ++mi)
        #pragma unroll
        for (int ni = 0; ni < 4; ++ni)
          acc[mi][ni] = __builtin_amdgcn_mfma_f32_16x16x32_bf16(a[mi], bf[ni][0], acc[mi][ni], 0, 0, 0);
      __builtin_amdgcn_s_setprio(0);
      __builtin_amdgcn_s_barrier();
    }

    // ---------- ph2: G2=(msub0,kk1) | stage B-h1(T+1) | vmcnt(4)
    {
      s16x8 a[4];
      #pragma unroll
      for (int mi = 0; mi < 4; ++mi)
        a[mi] = *(const s16x8*)(Ac + aRow + mi * 1024 + (c0 ^ 32));
      #pragma unroll
      for (int ni = 0; ni < 4; ++ni)
        bf[ni][1] = *(const s16x8*)(Bc + bRow + ni * 1024 + (c0 ^ 32));
      GLD16(bS + (size_t)128 * IN_DIM, bD + 16384);
      GLD16(bS + (size_t)192 * IN_DIM, bD + 24576);
      __builtin_amdgcn_s_barrier();
      __builtin_amdgcn_s_setprio(1);
      #pragma unroll
      for (int mi = 0; mi < 4; ++mi)
        #pragma unroll
        for (int ni = 0; ni < 4; ++ni)
          acc[mi][ni] = __builtin_amdgcn_mfma_f32_16x16x32_bf16(a[mi], bf[ni][1], acc[mi][ni], 0, 0, 0);
      __builtin_amdgcn_s_setprio(0);
      asm volatile("s_waitcnt vmcnt(4)" ::: "memory");  // A-odd(T) landed (ph3 reads)
      __builtin_amdgcn_s_barrier();
    }

    // ---------- ph3: G3=(msub1,kk0) | stage A-even(T+1)
    {
      s16x8 a[4];
      #pragma unroll
      for (int mi = 0; mi < 4; ++mi)
        a[mi] = *(const s16x8*)(Ac + aRow + (4 + mi) * 1024 + c0);
      GLD16(aS,                        aD);
      GLD16(aS + (size_t)128 * IN_DIM, aD + 16384);
      __builtin_amdgcn_s_barrier();
      __builtin_amdgcn_s_setprio(1);
      #pragma unroll
      for (int mi = 0; mi < 4; ++mi)
        #pragma unroll
        for (int ni = 0; ni < 4; ++ni)
          acc[4 + mi][ni] = __builtin_amdgcn_mfma_f32_16x16x32_bf16(a[mi], bf[ni][0], acc[4 + mi][ni], 0, 0, 0);
      __builtin_amdgcn_s_setprio(0);
      __builtin_amdgcn_s_barrier();
    }

    // ---------- ph4: G4=(msub1,kk1) | stage A-odd(T+1) | vmcnt(2)
    {
      s16x8 a[4];
      #pragma unroll
      for (int mi = 0; mi < 4; ++mi)
        a[mi] = *(const s16x8*)(Ac + aRow + (4 + mi) * 1024 + (c0 ^ 32));
      GLD16(aS + (size_t)64  * IN_DIM, aD + 8192);
      GLD16(aS + (size_t)192 * IN_DIM, aD + 24576);
      __builtin_amdgcn_s_barrier();
      __builtin_amdgcn_s_setprio(1);
      #pragma unroll
      for (int mi = 0; mi < 4; ++mi)
        #pragma unroll
        for (int ni = 0; ni < 4; ++ni)
          acc[4 + mi][ni] = __builtin_amdgcn_mfma_f32_16x16x32_bf16(a[mi], bf[ni][1], acc[4 + mi][ni], 0, 0, 0);
      __builtin_amdgcn_s_setprio(0);
      asm volatile("s_waitcnt vmcnt(2)" ::: "memory");  // B+A-even(T+1) landed (T+1 ph1/ph2 reads)
      __builtin_amdgcn_s_barrier();
    }
  }

  // ---------- epilogue: D lane map col=lane&15, row=(lane>>4)*4 + r
  const int row0 = bm * 256 + wm * 128 + lq * 4;
  const int col0 = bn * 256 + wn * 64 + lrow;
  #pragma unroll
  for (int mi = 0; mi < 8; ++mi) {
    const int row = row0 + mi * 16;
    const f32x4 sc4 = *(const f32x4*)(scale + row);
    #pragma unroll
    for (int ni = 0; ni < 4; ++ni) {
      const int col = col0 + ni * 16;
      const float bcol = bias[col];
      #pragma unroll
      for (int r = 0; r < 4; ++r) {
        float v = acc[mi][ni][r] * sc4[r] + bcol;
        out[(size_t)(row + r) * OUT_DIM + col] = fmaxf(v, 0.0f);
      }
    }
  }
}

extern "C" void kernel_launch(void* const* d_in, const int* in_sizes, int n_in,
                              void* d_out, int out_size, void* d_ws, size_t ws_size,
                              hipStream_t stream) {
  const float* x = (const float*)d_in[0];
  const float* W = (const float*)d_in[1];
  const float* b = (const float*)d_in[2];
  float* out = (float*)d_out;

  char* ws = (char*)d_ws;
  unsigned short* xn    = (unsigned short*)ws;                                  // 67108864 B
  unsigned short* Wb    = (unsigned short*)(ws + (size_t)67108864);             //  8388608 B
  float*          scale = (float*)(ws + (size_t)67108864 + (size_t)8388608);    //    65536 B

  prep_kernel<<<PREP_X_BLOCKS + PREP_W_BLOCKS, 256, 0, stream>>>(x, xn, scale, W, Wb);

  gemm_kernel<<<(OUT_DIM / 256) * (B_ROWS / 256), 512, 0, stream>>>(xn, Wb, scale, b, out);
}